// Round 8
// baseline (165.900 us; speedup 1.0000x reference)
//
#include <hip/hip_runtime.h>
#include <math.h>

#define N_NODES 100000
#define N_EDGES 1200000
#define F_IN    64
#define F_HID   16
#define F_OUT   40

#define BK_SHIFT 7                     // 128 nodes per bucket
#define BK_NODES 128
#define NB 782                         // ceil(100000/128)
#define CAP 2048                       // bucket capacity (mean 1534) — power of 2
#define CAP_SHIFT 11
#define S1_EPB 2048                    // edges per binning block
#define BIN_BLOCKS ((N_EDGES + S1_EPB - 1) / S1_EPB)   // 586
#define N_TILES ((N_NODES + 15) / 16)                  // 6250
#define GEMM_BLOCKS ((N_TILES + 7) / 8)                // 782 (4 waves x 2 tiles)

typedef _Float16 v2h  __attribute__((ext_vector_type(2)));
typedef _Float16 v8hf __attribute__((ext_vector_type(8)));
typedef float    vf4  __attribute__((ext_vector_type(4)));

// ---------------------------------------------------------------- k1 (fused):
// blocks [0,586): bin edges by dst bucket into csr region (packed (src<<7)|localdst)
// blocks [586,586+782): MFMA dual-GEMM: t1 = x@W1_neigh, xs = x@W1_self + b1 (fp16)
__global__ __launch_bounds__(256)
void k1_bin_gemm(const int* __restrict__ src, const int* __restrict__ dst,
                 unsigned* __restrict__ cursor, unsigned* __restrict__ csr,
                 const float* __restrict__ x, const float* __restrict__ Wn,
                 const float* __restrict__ Ws, const float* __restrict__ b1,
                 _Float16* __restrict__ t1, _Float16* __restrict__ xs, int nE) {
    __shared__ unsigned cnt[NB];
    int tid = threadIdx.x;
    int bid = blockIdx.x;
    if (bid < BIN_BLOCKS) {
        // ---------------- binning (8 edges per thread) ----------------
        for (int i = tid; i < NB; i += 256) cnt[i] = 0u;
        __syncthreads();
        int tb = bid * S1_EPB + tid * 8;
        if (tb + 8 <= nE) {
            const int4* d4 = (const int4*)(dst + tb);
#pragma unroll
            for (int j = 0; j < 2; j++) {
                int4 v = d4[j];
                atomicAdd(&cnt[((unsigned)v.x) >> BK_SHIFT], 1u);
                atomicAdd(&cnt[((unsigned)v.y) >> BK_SHIFT], 1u);
                atomicAdd(&cnt[((unsigned)v.z) >> BK_SHIFT], 1u);
                atomicAdd(&cnt[((unsigned)v.w) >> BK_SHIFT], 1u);
            }
        } else {
            for (int e = tb; e < nE && e < tb + 8; e++)
                atomicAdd(&cnt[((unsigned)dst[e]) >> BK_SHIFT], 1u);
        }
        __syncthreads();
        // global reservation; cnt becomes the running within-bucket cursor
        for (int i = tid; i < NB; i += 256) {
            unsigned c = cnt[i];
            cnt[i] = c ? atomicAdd(&cursor[i], c) : 0u;
        }
        __syncthreads();
        if (tb + 8 <= nE) {
            const int4* d4 = (const int4*)(dst + tb);
            const int4* s4 = (const int4*)(src + tb);
#pragma unroll
            for (int j = 0; j < 2; j++) {
                int4 dv = d4[j];
                int4 sv = s4[j];
                int da[4] = {dv.x, dv.y, dv.z, dv.w};
                int sa[4] = {sv.x, sv.y, sv.z, sv.w};
#pragma unroll
                for (int q = 0; q < 4; q++) {
                    unsigned d = (unsigned)da[q];
                    unsigned b = d >> BK_SHIFT;
                    unsigned pos = atomicAdd(&cnt[b], 1u);
                    if (pos < CAP)
                        csr[(b << CAP_SHIFT) + pos] = (((unsigned)sa[q]) << BK_SHIFT) | (d & (BK_NODES - 1));
                }
            }
        } else {
            for (int e = tb; e < nE && e < tb + 8; e++) {
                unsigned d = (unsigned)dst[e];
                unsigned b = d >> BK_SHIFT;
                unsigned pos = atomicAdd(&cnt[b], 1u);
                if (pos < CAP)
                    csr[(b << CAP_SHIFT) + pos] = (((unsigned)src[e]) << BK_SHIFT) | (d & (BK_NODES - 1));
            }
        }
    } else {
        // ---------------- MFMA dual GEMM (no LDS) ----------------
        // one wave per 16-row tile, 2 tiles per wave
        int wv = tid >> 6;
        int lane = tid & 63;
        int mrow = lane & 15;              // A row / C col index
        int quad = lane >> 4;              // 0..3
        int col = mrow;                    // B/C column
        // B fragments: lane holds W[k = kk + quad*8 + j][col], j=0..7
        v8hf bn0, bn1, bs0, bs1;
#pragma unroll
        for (int j = 0; j < 8; j++) {
            int k0 = quad * 8 + j;
            bn0[j] = (_Float16)Wn[k0 * F_HID + col];
            bs0[j] = (_Float16)Ws[k0 * F_HID + col];
            bn1[j] = (_Float16)Wn[(k0 + 32) * F_HID + col];
            bs1[j] = (_Float16)Ws[(k0 + 32) * F_HID + col];
        }
        float bias = b1[col];
        int gw = (bid - BIN_BLOCKS) * 4 + wv;
#pragma unroll
        for (int t = 0; t < 2; t++) {
            int tile = gw * 2 + t;
            if (tile >= N_TILES) break;
            int row0 = tile * 16;
            const float* xr = x + (size_t)(row0 + mrow) * F_IN;
            float4 x0 = *(const float4*)(xr + quad * 8);
            float4 x1 = *(const float4*)(xr + quad * 8 + 4);
            float4 x2 = *(const float4*)(xr + 32 + quad * 8);
            float4 x3 = *(const float4*)(xr + 32 + quad * 8 + 4);
            v8hf a0, a1;
            a0[0] = (_Float16)x0.x; a0[1] = (_Float16)x0.y;
            a0[2] = (_Float16)x0.z; a0[3] = (_Float16)x0.w;
            a0[4] = (_Float16)x1.x; a0[5] = (_Float16)x1.y;
            a0[6] = (_Float16)x1.z; a0[7] = (_Float16)x1.w;
            a1[0] = (_Float16)x2.x; a1[1] = (_Float16)x2.y;
            a1[2] = (_Float16)x2.z; a1[3] = (_Float16)x2.w;
            a1[4] = (_Float16)x3.x; a1[5] = (_Float16)x3.y;
            a1[6] = (_Float16)x3.z; a1[7] = (_Float16)x3.w;
            vf4 accn = {0.f, 0.f, 0.f, 0.f};
            vf4 accs = {bias, bias, bias, bias};
            accn = __builtin_amdgcn_mfma_f32_16x16x32_f16(a0, bn0, accn, 0, 0, 0);
            accn = __builtin_amdgcn_mfma_f32_16x16x32_f16(a1, bn1, accn, 0, 0, 0);
            accs = __builtin_amdgcn_mfma_f32_16x16x32_f16(a0, bs0, accs, 0, 0, 0);
            accs = __builtin_amdgcn_mfma_f32_16x16x32_f16(a1, bs1, accs, 0, 0, 0);
            // C/D: col = lane&15, row = quad*4 + r
#pragma unroll
            for (int r = 0; r < 4; r++) {
                int row = row0 + quad * 4 + r;
                t1[row * F_HID + col] = (_Float16)accn[r];
                xs[row * F_HID + col] = (_Float16)accs[r];
            }
        }
    }
}

// ---------------------------------------------------------------- k2 (fused):
// per-bucket counting sort in LDS + agg1 gather-sum + layer1 epilogue.
// Sorted src list stays in LDS for the aggregation; also written back to csr
// (coalesced) for agg2. h overwrites xs in place.
__global__ __launch_bounds__(512)
void k2_sort_agg1(const unsigned* __restrict__ cursor, unsigned* __restrict__ csr,
                  unsigned* __restrict__ node_info,
                  const _Float16* __restrict__ t1, _Float16* __restrict__ xsh) {
    __shared__ unsigned words[CAP];
    __shared__ unsigned sorted[CAP];
    __shared__ unsigned hist[BK_NODES];
    __shared__ unsigned lcur[BK_NODES];
    __shared__ unsigned begs[BK_NODES];
    int tid = threadIdx.x;                 // 512
    int b = blockIdx.x;
    unsigned count = cursor[b]; if (count > CAP) count = CAP;
    unsigned* reg = csr + ((size_t)b << CAP_SHIFT);
    for (unsigned i = tid; i < count; i += 512) words[i] = reg[i];
    if (tid < BK_NODES) hist[tid] = 0u;
    __syncthreads();
    for (unsigned i = tid; i < count; i += 512)
        atomicAdd(&hist[words[i] & (BK_NODES - 1)], 1u);
    __syncthreads();
    unsigned hv = (tid < BK_NODES) ? hist[tid] : 0u;
    __syncthreads();
    for (int d = 1; d < BK_NODES; d <<= 1) {           // inclusive Hillis-Steele
        unsigned t = (tid < BK_NODES && tid >= d) ? hist[tid - d] : 0u;
        __syncthreads();
        if (tid < BK_NODES) hist[tid] += t;
        __syncthreads();
    }
    if (tid < BK_NODES) {
        unsigned excl = hist[tid] - hv;                // exclusive local begin
        begs[tid] = excl;
        lcur[tid] = excl;
        int node = (b << BK_SHIFT) + tid;
        if (node < N_NODES) node_info[node] = (excl << 16) | hv;
    }
    __syncthreads();
    for (unsigned i = tid; i < count; i += 512) {
        unsigned w = words[i];
        unsigned pos = atomicAdd(&lcur[w & (BK_NODES - 1)], 1u);
        sorted[pos] = w >> BK_SHIFT;                   // plain src index
    }
    __syncthreads();
    // write back sorted csr for agg2 (coalesced)
    for (unsigned i = tid; i < count; i += 512) reg[i] = sorted[i];

    // ---------------- aggregation + layer1 epilogue ----------------
    int grp = tid >> 3;                    // 64 groups
    int f = tid & 7;                       // channel pair
    const v2h* t2 = (const v2h*)t1;
#pragma unroll
    for (int half = 0; half < 2; half++) {
        int ln = grp + half * 64;          // local node
        int node = (b << BK_SHIFT) + ln;
        if (node >= N_NODES) continue;
        unsigned beg = begs[ln];
        unsigned end = lcur[ln];           // lcur == end after scatter
        float ax = 0.f, ay = 0.f;
        unsigned e = beg;
        for (; e + 4 <= end; e += 4) {     // 4 independent gathers in flight
            unsigned s0 = sorted[e], s1 = sorted[e + 1];
            unsigned s2 = sorted[e + 2], s3 = sorted[e + 3];
            v2h v0 = t2[s0 * 8 + f], v1 = t2[s1 * 8 + f];
            v2h v2 = t2[s2 * 8 + f], v3 = t2[s3 * 8 + f];
            ax += (float)v0.x + (float)v1.x + (float)v2.x + (float)v3.x;
            ay += (float)v0.y + (float)v1.y + (float)v2.y + (float)v3.y;
        }
        for (; e < end; e++) {
            v2h v = t2[sorted[e] * 8 + f];
            ax += (float)v.x; ay += (float)v.y;
        }
        float inv = 1.0f / fmaxf((float)(end - beg), 1.0f);
        int g = node * 8 + f;
        v2h xv = ((const v2h*)xsh)[g];
        v2h hvv;
        hvv.x = (_Float16)fmaxf((float)xv.x + ax * inv, 0.f);
        hvv.y = (_Float16)fmaxf((float)xv.y + ay * inv, 0.f);
        ((v2h*)xsh)[g] = hvv;
    }
}

// ---------------------------------------------------------------- k3: agg2 gather-sum + layer2 + log_softmax
__global__ __launch_bounds__(256)
void agg2_kernel(const unsigned* __restrict__ node_info, const unsigned* __restrict__ csr,
                 const _Float16* __restrict__ h,
                 const float* __restrict__ Ws, const float* __restrict__ Wn,
                 const float* __restrict__ b2, float* __restrict__ out, int n) {
    __shared__ float sWs[F_HID * F_OUT];
    __shared__ float sWn[F_HID * F_OUT];
    __shared__ float sb[F_OUT];
    int tid = threadIdx.x;
    for (int i = tid; i < F_HID * F_OUT; i += 256) { sWs[i] = Ws[i]; sWn[i] = Wn[i]; }
    if (tid < F_OUT) sb[tid] = b2[tid];
    __syncthreads();
    int g = blockIdx.x * 256 + tid;
    int node = g >> 3;
    int f = g & 7;
    if (node >= n) return;
    unsigned info = node_info[node];
    int beg = ((node >> BK_SHIFT) << CAP_SHIFT) + (int)(info >> 16);
    int cnt = (int)(info & 0xFFFFu);
    int end = beg + cnt;
    const v2h* h2 = (const v2h*)h;
    float ax = 0.f, ay = 0.f;
    int e = beg;
    for (; e + 4 <= end; e += 4) {
        unsigned s0 = csr[e], s1 = csr[e + 1], s2 = csr[e + 2], s3 = csr[e + 3];
        v2h v0 = h2[s0 * 8 + f], v1 = h2[s1 * 8 + f];
        v2h v2 = h2[s2 * 8 + f], v3 = h2[s3 * 8 + f];
        ax += (float)v0.x + (float)v1.x + (float)v2.x + (float)v3.x;
        ay += (float)v0.y + (float)v1.y + (float)v2.y + (float)v3.y;
    }
    for (; e < end; e++) {
        v2h v = h2[csr[e] * 8 + f];
        ax += (float)v.x; ay += (float)v.y;
    }
    float inv = 1.0f / fmaxf((float)cnt, 1.0f);
    ax *= inv; ay *= inv;
    v2h hs = h2[g];
    float hx = (float)hs.x, hy = (float)hs.y;
    float arow[F_HID], hrow[F_HID];
#pragma unroll
    for (int k = 0; k < 8; k++) {
        arow[2 * k]     = __shfl(ax, k, 8);
        arow[2 * k + 1] = __shfl(ay, k, 8);
        hrow[2 * k]     = __shfl(hx, k, 8);
        hrow[2 * k + 1] = __shfl(hy, k, 8);
    }
    float logit[5];
    float m = -INFINITY;
#pragma unroll
    for (int j = 0; j < 5; j++) {
        int c = j * 8 + f;
        float s = sb[c];
#pragma unroll
        for (int k = 0; k < F_HID; k++)
            s += hrow[k] * sWs[k * F_OUT + c] + arow[k] * sWn[k * F_OUT + c];
        logit[j] = s;
        m = fmaxf(m, s);
    }
    m = fmaxf(m, __shfl_xor(m, 1, 8));
    m = fmaxf(m, __shfl_xor(m, 2, 8));
    m = fmaxf(m, __shfl_xor(m, 4, 8));
    float sum = 0.f;
#pragma unroll
    for (int j = 0; j < 5; j++) sum += __expf(logit[j] - m);
    sum += __shfl_xor(sum, 1, 8);
    sum += __shfl_xor(sum, 2, 8);
    sum += __shfl_xor(sum, 4, 8);
    float lse = m + __logf(sum);
#pragma unroll
    for (int j = 0; j < 5; j++)
        out[node * F_OUT + j * 8 + f] = logit[j] - lse;
}

extern "C" void kernel_launch(void* const* d_in, const int* in_sizes, int n_in,
                              void* d_out, int out_size, void* d_ws, size_t ws_size,
                              hipStream_t stream) {
    const float* x        = (const float*)d_in[0];
    const int*   edges    = (const int*)d_in[1];    // (2, N_EDGES) row-major
    const float* W1_self  = (const float*)d_in[2];
    const float* W1_neigh = (const float*)d_in[3];
    const float* b1       = (const float*)d_in[4];
    const float* W2_self  = (const float*)d_in[5];
    const float* W2_neigh = (const float*)d_in[6];
    const float* b2       = (const float*)d_in[7];
    float* out = (float*)d_out;

    const int* src = edges;
    const int* dst = edges + N_EDGES;

    // ws layout (268 MB available; generous slabs):
    //   cursor    @ 0      (4 KB)
    //   node_info @ 1 MB   (400 KB)
    //   csr       @ 2 MB   (NB<<11 words = 6.4 MB)
    //   t1        @ 16 MB  (3.2 MB fp16)
    //   xs/h      @ 24 MB  (3.2 MB fp16)
    char* base = (char*)d_ws;
    unsigned* cursor    = (unsigned*)base;
    unsigned* node_info = (unsigned*)(base + (1u << 20));
    unsigned* csr       = (unsigned*)(base + (2u << 20));
    _Float16* t1        = (_Float16*)(base + (16u << 20));
    _Float16* xsh       = (_Float16*)(base + (24u << 20));

    hipMemsetAsync(cursor, 0, 4096, stream);

    k1_bin_gemm<<<BIN_BLOCKS + GEMM_BLOCKS, 256, 0, stream>>>(
        src, dst, cursor, csr, x, W1_neigh, W1_self, b1, t1, xsh, N_EDGES);
    k2_sort_agg1<<<NB, 512, 0, stream>>>(cursor, csr, node_info, t1, xsh);
    agg2_kernel<<<(N_NODES * 8) / 256, 256, 0, stream>>>(node_info, csr, xsh,
                                                         W2_self, W2_neigh, b2, out, N_NODES);
}

// Round 9
// 150.909 us; speedup vs baseline: 1.0993x; 1.0993x over previous
//
#include <hip/hip_runtime.h>
#include <math.h>

#define N_NODES 100000
#define N_EDGES 1200000
#define F_IN    64
#define F_HID   16
#define F_OUT   40

#define BK_SHIFT 7                     // 128 nodes per bucket
#define BK_NODES 128
#define NB 782                         // ceil(100000/128)
#define CAP 2048                       // per-bucket total capacity (mean 1534)
#define CAP_SHIFT 11
#define SEG_CAP 32                     // per-(block,bucket) capacity (mean 10.5, +6.8 sigma)
#define PADB 160                       // padded BIN_BLOCKS for scan
#define S1_EPB 8192                    // edges per bin block
#define BIN_BLOCKS 147                 // ceil(1.2M / 8192)
#define N_TILES ((N_NODES + 15) / 16)  // 6250
#define GEMM_BLOCKS ((N_TILES + 7) / 8)// 782 (4 waves x 2 tiles)

typedef _Float16 v4h  __attribute__((ext_vector_type(4)));
typedef _Float16 v8hf __attribute__((ext_vector_type(8)));
typedef float    vf4  __attribute__((ext_vector_type(4)));

// ---------------------------------------------------------------- k1 (fused):
// blocks [0,147): bin edges into PRIVATE per-block regions — zero global atomics
// blocks [147,147+782): MFMA dual-GEMM: t1 = x@W1_neigh, xs = x@W1_self + b1 (fp16)
__global__ __launch_bounds__(256)
void k1_bin_gemm(const int* __restrict__ src, const int* __restrict__ dst,
                 unsigned short* __restrict__ cnt_t, unsigned* __restrict__ region,
                 const float* __restrict__ x, const float* __restrict__ Wn,
                 const float* __restrict__ Ws, const float* __restrict__ b1,
                 _Float16* __restrict__ t1, _Float16* __restrict__ xs, int nE) {
    __shared__ unsigned cnt[NB];
    int tid = threadIdx.x;
    int bid = blockIdx.x;
    if (bid < BIN_BLOCKS) {
        // ---------------- binning: LDS cursors only ----------------
        for (int i = tid; i < NB; i += 256) cnt[i] = 0u;
        __syncthreads();
        int tb = bid * S1_EPB + tid * 32;
        unsigned rbase = (unsigned)bid * NB;
        if (tb + 32 <= nE) {
            const int4* d4 = (const int4*)(dst + tb);
            const int4* s4 = (const int4*)(src + tb);
#pragma unroll
            for (int j = 0; j < 8; j++) {
                int4 dv = d4[j];
                int4 sv = s4[j];
                int da[4] = {dv.x, dv.y, dv.z, dv.w};
                int sa[4] = {sv.x, sv.y, sv.z, sv.w};
#pragma unroll
                for (int q = 0; q < 4; q++) {
                    unsigned d = (unsigned)da[q];
                    unsigned b = d >> BK_SHIFT;
                    unsigned pos = atomicAdd(&cnt[b], 1u);   // LDS atomic
                    if (pos < SEG_CAP)
                        region[(rbase + b) * SEG_CAP + pos] =
                            (((unsigned)sa[q]) << BK_SHIFT) | (d & (BK_NODES - 1));
                }
            }
        } else {
            for (int e = tb; e < nE && e < tb + 32; e++) {
                unsigned d = (unsigned)dst[e];
                unsigned b = d >> BK_SHIFT;
                unsigned pos = atomicAdd(&cnt[b], 1u);
                if (pos < SEG_CAP)
                    region[(rbase + b) * SEG_CAP + pos] =
                        (((unsigned)src[e]) << BK_SHIFT) | (d & (BK_NODES - 1));
            }
        }
        __syncthreads();
        for (int i = tid; i < NB; i += 256) {
            unsigned c = cnt[i];
            cnt_t[i * PADB + bid] = (unsigned short)(c < SEG_CAP ? c : SEG_CAP);
        }
    } else {
        // ---------------- MFMA dual GEMM (no LDS) ----------------
        int wv = tid >> 6;
        int lane = tid & 63;
        int mrow = lane & 15;              // A row / C col index
        int quad = lane >> 4;              // 0..3
        int col = mrow;
        v8hf bn0, bn1, bs0, bs1;
#pragma unroll
        for (int j = 0; j < 8; j++) {
            int k0 = quad * 8 + j;
            bn0[j] = (_Float16)Wn[k0 * F_HID + col];
            bs0[j] = (_Float16)Ws[k0 * F_HID + col];
            bn1[j] = (_Float16)Wn[(k0 + 32) * F_HID + col];
            bs1[j] = (_Float16)Ws[(k0 + 32) * F_HID + col];
        }
        float bias = b1[col];
        int gw = (bid - BIN_BLOCKS) * 4 + wv;
#pragma unroll
        for (int t = 0; t < 2; t++) {
            int tile = gw * 2 + t;
            if (tile >= N_TILES) break;
            int row0 = tile * 16;
            const float* xr = x + (size_t)(row0 + mrow) * F_IN;
            float4 x0 = *(const float4*)(xr + quad * 8);
            float4 x1 = *(const float4*)(xr + quad * 8 + 4);
            float4 x2 = *(const float4*)(xr + 32 + quad * 8);
            float4 x3 = *(const float4*)(xr + 32 + quad * 8 + 4);
            v8hf a0, a1;
            a0[0] = (_Float16)x0.x; a0[1] = (_Float16)x0.y;
            a0[2] = (_Float16)x0.z; a0[3] = (_Float16)x0.w;
            a0[4] = (_Float16)x1.x; a0[5] = (_Float16)x1.y;
            a0[6] = (_Float16)x1.z; a0[7] = (_Float16)x1.w;
            a1[0] = (_Float16)x2.x; a1[1] = (_Float16)x2.y;
            a1[2] = (_Float16)x2.z; a1[3] = (_Float16)x2.w;
            a1[4] = (_Float16)x3.x; a1[5] = (_Float16)x3.y;
            a1[6] = (_Float16)x3.z; a1[7] = (_Float16)x3.w;
            vf4 accn = {0.f, 0.f, 0.f, 0.f};
            vf4 accs = {bias, bias, bias, bias};
            accn = __builtin_amdgcn_mfma_f32_16x16x32_f16(a0, bn0, accn, 0, 0, 0);
            accn = __builtin_amdgcn_mfma_f32_16x16x32_f16(a1, bn1, accn, 0, 0, 0);
            accs = __builtin_amdgcn_mfma_f32_16x16x32_f16(a0, bs0, accs, 0, 0, 0);
            accs = __builtin_amdgcn_mfma_f32_16x16x32_f16(a1, bs1, accs, 0, 0, 0);
#pragma unroll
            for (int r = 0; r < 4; r++) {
                int row = row0 + quad * 4 + r;
                t1[row * F_HID + col] = (_Float16)accn[r];
                xs[row * F_HID + col] = (_Float16)accs[r];
            }
        }
    }
}

// ---------------------------------------------------------------- k2 (fused):
// per-bucket: merge 147 private segments -> LDS, counting sort, write sorted
// csr, agg1 gather-sum (4 lanes/node, v4h) + layer1 epilogue (h overwrites xs).
__global__ __launch_bounds__(512)
void k2_sort_agg1(const unsigned short* __restrict__ cnt_t, const unsigned* __restrict__ region,
                  unsigned* __restrict__ csr, unsigned* __restrict__ node_info,
                  const _Float16* __restrict__ t1, _Float16* __restrict__ xsh) {
    __shared__ unsigned scnt[PADB];        // inclusive scan of segment counts
    __shared__ unsigned segbase[BIN_BLOCKS];
    __shared__ unsigned words[CAP];
    __shared__ unsigned sorted[CAP];
    __shared__ unsigned hist[BK_NODES];
    __shared__ unsigned lcur[BK_NODES];
    __shared__ unsigned begs[BK_NODES];
    int tid = threadIdx.x;                 // 512
    int b = blockIdx.x;

    unsigned myc = 0u;
    if (tid < PADB) {
        myc = (tid < BIN_BLOCKS) ? (unsigned)cnt_t[b * PADB + tid] : 0u;
        scnt[tid] = myc;
    }
    __syncthreads();
    for (int d = 1; d < PADB; d <<= 1) {   // inclusive Hillis-Steele over PADB
        unsigned t = (tid < PADB && tid >= d) ? scnt[tid - d] : 0u;
        __syncthreads();
        if (tid < PADB) scnt[tid] += t;
        __syncthreads();
    }
    if (tid < BIN_BLOCKS) segbase[tid] = scnt[tid] - myc;
    __syncthreads();
    unsigned count = scnt[BIN_BLOCKS - 1];
    if (count > CAP) count = CAP;

    // merge segments: 16 half-waves, one segment per half-wave per iteration
    int hw = tid >> 5, lane = tid & 31;
    for (int j = hw; j < BIN_BLOCKS; j += 16) {
        unsigned base = segbase[j];
        unsigned c = scnt[j] - base;
        if (lane < c) {
            unsigned pos = base + lane;
            if (pos < CAP)
                words[pos] = region[((unsigned)j * NB + b) * SEG_CAP + lane];
        }
    }
    if (tid < BK_NODES) hist[tid] = 0u;
    __syncthreads();

    // counting sort by local node
    for (unsigned i = tid; i < count; i += 512)
        atomicAdd(&hist[words[i] & (BK_NODES - 1)], 1u);
    __syncthreads();
    unsigned hv = (tid < BK_NODES) ? hist[tid] : 0u;
    __syncthreads();
    for (int d = 1; d < BK_NODES; d <<= 1) {
        unsigned t = (tid < BK_NODES && tid >= d) ? hist[tid - d] : 0u;
        __syncthreads();
        if (tid < BK_NODES) hist[tid] += t;
        __syncthreads();
    }
    if (tid < BK_NODES) {
        unsigned excl = hist[tid] - hv;
        begs[tid] = excl;
        lcur[tid] = excl;
        int node = (b << BK_SHIFT) + tid;
        if (node < N_NODES) node_info[node] = (excl << 16) | hv;
    }
    __syncthreads();
    for (unsigned i = tid; i < count; i += 512) {
        unsigned w = words[i];
        unsigned pos = atomicAdd(&lcur[w & (BK_NODES - 1)], 1u);
        sorted[pos] = w >> BK_SHIFT;
    }
    __syncthreads();
    unsigned* reg = csr + ((size_t)b << CAP_SHIFT);
    for (unsigned i = tid; i < count; i += 512) reg[i] = sorted[i];

    // ---------------- agg1: 4 lanes per node, v4h gathers ----------------
    int grp = tid >> 2;                    // 0..127 local node
    int f = tid & 3;                       // channel quad
    int node = (b << BK_SHIFT) + grp;
    if (node >= N_NODES) return;
    unsigned beg = begs[grp];
    unsigned end = lcur[grp];
    const v4h* t4 = (const v4h*)t1;
    float a0 = 0.f, a1 = 0.f, a2 = 0.f, a3 = 0.f;
    unsigned e = beg;
    for (; e + 4 <= end; e += 4) {
        unsigned s0 = sorted[e], s1 = sorted[e + 1];
        unsigned s2 = sorted[e + 2], s3 = sorted[e + 3];
        v4h v0 = t4[s0 * 4 + f], v1 = t4[s1 * 4 + f];
        v4h v2 = t4[s2 * 4 + f], v3 = t4[s3 * 4 + f];
        a0 += (float)v0[0] + (float)v1[0] + (float)v2[0] + (float)v3[0];
        a1 += (float)v0[1] + (float)v1[1] + (float)v2[1] + (float)v3[1];
        a2 += (float)v0[2] + (float)v1[2] + (float)v2[2] + (float)v3[2];
        a3 += (float)v0[3] + (float)v1[3] + (float)v2[3] + (float)v3[3];
    }
    for (; e < end; e++) {
        v4h v = t4[sorted[e] * 4 + f];
        a0 += (float)v[0]; a1 += (float)v[1]; a2 += (float)v[2]; a3 += (float)v[3];
    }
    float inv = 1.0f / fmaxf((float)(end - beg), 1.0f);
    v4h* x4 = (v4h*)xsh;
    v4h xv = x4[node * 4 + f];
    v4h hv4;
    hv4[0] = (_Float16)fmaxf((float)xv[0] + a0 * inv, 0.f);
    hv4[1] = (_Float16)fmaxf((float)xv[1] + a1 * inv, 0.f);
    hv4[2] = (_Float16)fmaxf((float)xv[2] + a2 * inv, 0.f);
    hv4[3] = (_Float16)fmaxf((float)xv[3] + a3 * inv, 0.f);
    x4[node * 4 + f] = hv4;
}

// ---------------------------------------------------------------- k3: agg2 (4 lanes/node)
// gather-sum of h + layer2 GEMM + log_softmax; lane f owns classes f*10..f*10+9
__global__ __launch_bounds__(256)
void agg2_kernel(const unsigned* __restrict__ node_info, const unsigned* __restrict__ csr,
                 const _Float16* __restrict__ h,
                 const float* __restrict__ Ws, const float* __restrict__ Wn,
                 const float* __restrict__ b2, float* __restrict__ out, int n) {
    __shared__ float sWs[F_HID * F_OUT];
    __shared__ float sWn[F_HID * F_OUT];
    __shared__ float sb[F_OUT];
    int tid = threadIdx.x;
    for (int i = tid; i < F_HID * F_OUT; i += 256) { sWs[i] = Ws[i]; sWn[i] = Wn[i]; }
    if (tid < F_OUT) sb[tid] = b2[tid];
    __syncthreads();
    int g = blockIdx.x * 256 + tid;
    int node = g >> 2;
    int f = g & 3;
    if (node >= n) return;
    unsigned info = node_info[node];
    int beg = ((node >> BK_SHIFT) << CAP_SHIFT) + (int)(info >> 16);
    int cnt = (int)(info & 0xFFFFu);
    int end = beg + cnt;
    const v4h* h4 = (const v4h*)h;
    float a0 = 0.f, a1 = 0.f, a2 = 0.f, a3 = 0.f;
    int e = beg;
    for (; e + 4 <= end; e += 4) {
        unsigned s0 = csr[e], s1 = csr[e + 1], s2 = csr[e + 2], s3 = csr[e + 3];
        v4h v0 = h4[s0 * 4 + f], v1 = h4[s1 * 4 + f];
        v4h v2 = h4[s2 * 4 + f], v3 = h4[s3 * 4 + f];
        a0 += (float)v0[0] + (float)v1[0] + (float)v2[0] + (float)v3[0];
        a1 += (float)v0[1] + (float)v1[1] + (float)v2[1] + (float)v3[1];
        a2 += (float)v0[2] + (float)v1[2] + (float)v2[2] + (float)v3[2];
        a3 += (float)v0[3] + (float)v1[3] + (float)v2[3] + (float)v3[3];
    }
    for (; e < end; e++) {
        v4h v = h4[csr[e] * 4 + f];
        a0 += (float)v[0]; a1 += (float)v[1]; a2 += (float)v[2]; a3 += (float)v[3];
    }
    float inv = 1.0f / fmaxf((float)cnt, 1.0f);
    a0 *= inv; a1 *= inv; a2 *= inv; a3 *= inv;
    v4h hs = h4[node * 4 + f];
    float h0 = (float)hs[0], h1 = (float)hs[1], h2 = (float)hs[2], h3 = (float)hs[3];
    // exchange within 4-lane group: lane k holds channels 4k..4k+3
    float arow[F_HID], hrow[F_HID];
#pragma unroll
    for (int k = 0; k < 4; k++) {
        arow[4 * k + 0] = __shfl(a0, k, 4);
        arow[4 * k + 1] = __shfl(a1, k, 4);
        arow[4 * k + 2] = __shfl(a2, k, 4);
        arow[4 * k + 3] = __shfl(a3, k, 4);
        hrow[4 * k + 0] = __shfl(h0, k, 4);
        hrow[4 * k + 1] = __shfl(h1, k, 4);
        hrow[4 * k + 2] = __shfl(h2, k, 4);
        hrow[4 * k + 3] = __shfl(h3, k, 4);
    }
    float logit[10];
    float m = -INFINITY;
#pragma unroll
    for (int j = 0; j < 10; j++) {
        int c = f * 10 + j;
        float s = sb[c];
#pragma unroll
        for (int k = 0; k < F_HID; k++)
            s += hrow[k] * sWs[k * F_OUT + c] + arow[k] * sWn[k * F_OUT + c];
        logit[j] = s;
        m = fmaxf(m, s);
    }
    m = fmaxf(m, __shfl_xor(m, 1, 4));
    m = fmaxf(m, __shfl_xor(m, 2, 4));
    float sum = 0.f;
#pragma unroll
    for (int j = 0; j < 10; j++) sum += __expf(logit[j] - m);
    sum += __shfl_xor(sum, 1, 4);
    sum += __shfl_xor(sum, 2, 4);
    float lse = m + __logf(sum);
#pragma unroll
    for (int j = 0; j < 10; j++)
        out[node * F_OUT + f * 10 + j] = logit[j] - lse;
}

extern "C" void kernel_launch(void* const* d_in, const int* in_sizes, int n_in,
                              void* d_out, int out_size, void* d_ws, size_t ws_size,
                              hipStream_t stream) {
    const float* x        = (const float*)d_in[0];
    const int*   edges    = (const int*)d_in[1];    // (2, N_EDGES) row-major
    const float* W1_self  = (const float*)d_in[2];
    const float* W1_neigh = (const float*)d_in[3];
    const float* b1       = (const float*)d_in[4];
    const float* W2_self  = (const float*)d_in[5];
    const float* W2_neigh = (const float*)d_in[6];
    const float* b2       = (const float*)d_in[7];
    float* out = (float*)d_out;

    const int* src = edges;
    const int* dst = edges + N_EDGES;

    // ws layout (268 MB available):
    //   cnt_t     @ 0       NB*PADB u16      = 250,240 B
    //   node_info @ 1 MB    400,000 B
    //   csr       @ 2 MB    NB<<11 words     = 6,406,144 B
    //   region    @ 16 MB   147*NB*32 words  = 14,713,344 B
    //   t1        @ 32 MB   3.2 MB fp16
    //   xs/h      @ 40 MB   3.2 MB fp16
    char* base = (char*)d_ws;
    unsigned short* cnt_t    = (unsigned short*)base;
    unsigned*       node_info= (unsigned*)(base + (1u << 20));
    unsigned*       csr      = (unsigned*)(base + (2u << 20));
    unsigned*       region   = (unsigned*)(base + (16u << 20));
    _Float16*       t1       = (_Float16*)(base + (32u << 20));
    _Float16*       xsh      = (_Float16*)(base + (40u << 20));

    k1_bin_gemm<<<BIN_BLOCKS + GEMM_BLOCKS, 256, 0, stream>>>(
        src, dst, cnt_t, region, x, W1_neigh, W1_self, b1, t1, xsh, N_EDGES);
    k2_sort_agg1<<<NB, 512, 0, stream>>>(cnt_t, region, csr, node_info, t1, xsh);
    agg2_kernel<<<(N_NODES * 4 + 255) / 256, 256, 0, stream>>>(node_info, csr, xsh,
                                                               W2_self, W2_neigh, b2, out, N_NODES);
}